// Round 5
// baseline (480.870 us; speedup 1.0000x reference)
//
#include <hip/hip_runtime.h>
#include <hip/hip_fp8.h>
#include <cstdio>
#include <cstdint>

#define K_DIM 4096
#define N_DIM 4096
#define BKB 64                 // K-bytes per LDS tile
#define NT (K_DIM / BKB)       // 64 K-tiles

typedef int v4i __attribute__((ext_vector_type(4)));
typedef int v8i __attribute__((ext_vector_type(8)));
typedef float v16f __attribute__((ext_vector_type(16)));

// ---------------------------------------------------------------- amax ------
__global__ void amax_kernel(const float4* __restrict__ x, int n4,
                            unsigned* __restrict__ out) {
  int i = blockIdx.x * blockDim.x + threadIdx.x;
  int stride = gridDim.x * blockDim.x;
  float m = 0.f;
  for (; i < n4; i += stride) {
    float4 v = x[i];
    m = fmaxf(m, fmaxf(fmaxf(fabsf(v.x), fabsf(v.y)),
                       fmaxf(fabsf(v.z), fabsf(v.w))));
  }
#pragma unroll
  for (int off = 32; off > 0; off >>= 1)
    m = fmaxf(m, __shfl_down(m, off, 64));
  __shared__ float wred[4];
  int lane = threadIdx.x & 63, wid = threadIdx.x >> 6;
  if (lane == 0) wred[wid] = m;
  __syncthreads();
  if (threadIdx.x == 0) {
    m = fmaxf(fmaxf(wred[0], wred[1]), fmaxf(wred[2], wred[3]));
    atomicMax(out, __float_as_uint(m));  // bit-compare valid: m >= 0
  }
}

__device__ __forceinline__ float load_scale(const unsigned* p) {
  return fmaxf(__uint_as_float(*p) / 448.0f, 1e-12f);
}

__device__ __forceinline__ unsigned f2fp8(float v) {
  return (unsigned)__hip_cvt_float_to_fp8(v, __HIP_SATFINITE, __HIP_E4M3);
}

// ------------------------------------------------------------- quantize A ---
__global__ void quant1_kernel(const float4* __restrict__ x, uint4* __restrict__ q,
                              const unsigned* __restrict__ amax_bits, int n16) {
  float s = load_scale(amax_bits);
  int i = blockIdx.x * blockDim.x + threadIdx.x;
  int stride = gridDim.x * blockDim.x;
  for (; i < n16; i += stride) {
    unsigned w[4];
#pragma unroll
    for (int j = 0; j < 4; ++j) {
      float4 v = x[i * 4 + j];
      w[j] = f2fp8(v.x / s) | (f2fp8(v.y / s) << 8) |
             (f2fp8(v.z / s) << 16) | (f2fp8(v.w / s) << 24);
    }
    uint4 r; r.x = w[0]; r.y = w[1]; r.z = w[2]; r.w = w[3];
    q[i] = r;
  }
}

// ---------------------------- quantize B -> MFMA-fragment-blocked layout ----
// x: [K][N] fp32 -> Bq[n32][k64][lane][32B]: chunk (n32,k64) is the 2048-B
// fragment a wave consumes for B-subtile n32 at K-tile k64: lane l = kh*32+r5
// holds Bt[n32*32+r5][k64*64 + kh*32 .. +31]. Wave load = base + lane*32.
__global__ void quant2t_kernel(const float* __restrict__ x,
                               unsigned char* __restrict__ qt,
                               const unsigned* __restrict__ amax_bits) {
  float s = load_scale(amax_bits);
  __shared__ unsigned char tile[64][68];
  int tj = blockIdx.x & 63;   // N tile (2 chunks of 32)
  int ti = blockIdx.x >> 6;   // K tile
  int t = threadIdx.x;
  int c = t & 63;
  int r0 = (t >> 6) * 16;
#pragma unroll
  for (int rr = 0; rr < 16; ++rr) {
    int r = r0 + rr;
    float v = x[(size_t)(ti * 64 + r) * N_DIM + tj * 64 + c];
    tile[c][r] = (unsigned char)f2fp8(v / s);  // tile[n][k]
  }
  __syncthreads();
  int n = t >> 2;             // 0..63
  int kc = (t & 3) << 4;      // 0,16,32,48
  const unsigned* lp = (const unsigned*)&tile[n][kc];
  uint4 v; v.x = lp[0]; v.y = lp[1]; v.z = lp[2]; v.w = lp[3];
  int n32 = tj * 2 + (n >> 5);
  size_t dst = ((size_t)n32 * 64 + ti) * 2048 +
               (size_t)(((kc >> 5) * 32 + (n & 31)) * 32 + (kc & 31));
  *(uint4*)&qt[dst] = v;
}

// ------------------------------------------------------------------ GEMM ----
// 256x256 tile, 8 waves (2Mx4N), BK=64B, MX-scaled fp8 MFMA (scale exp 127 =
// exact 1.0) at 2x non-scaled fp8 rate.
// A: LDS ring-4 x 16KB, staged 3 tiles ahead via global_load_lds (linear dest,
//    pre-swizzled source); fragments ds_read one tile ahead.
// B: NO LDS — global->register from the fragment-blocked Bq layout, one tile
//    ahead (L2/L3-resident, perfectly coalesced: 2048B contiguous per wave).
// DS pipe/tile drops 128KB -> 80KB < MFMA 1100cyc -> MFMA-bound.
#define GLOAD(src, dst)                                              \
  __builtin_amdgcn_global_load_lds(                                  \
      (const __attribute__((address_space(1))) void*)(src),          \
      (__attribute__((address_space(3))) void*)(dst), 16, 0, 0)

#define MFMA_SC(a, b, c)                                             \
  __builtin_amdgcn_mfma_scale_f32_32x32x64_f8f6f4(a, b, c, 0, 0, 0, 127, 0, 127)

__global__ __launch_bounds__(512, 2)
void gemm_fp8_kernel(const unsigned char* __restrict__ A,
                     const unsigned char* __restrict__ Bq,
                     float* __restrict__ C,
                     const unsigned* __restrict__ amax_bits) {
  __shared__ __align__(16) unsigned char lds[4][16384];

  int bid = blockIdx.x;
  int nwg = gridDim.x;                    // 1024, %8 == 0
  int swz = (bid & 7) * (nwg >> 3) + (bid >> 3);
  int brow = (swz >> 4) * 256;
  int bcol = (swz & 15) * 256;

  int t = threadIdx.x;
  int lane = t & 63, wid = t >> 6;
  int wm = wid >> 2, wn = wid & 3;        // wave quadrant: 2M x 4N
  int r5 = lane & 31;
  int khalf = lane >> 5;

  // A staging: dest linear (part*8192 + t*16), source column pre-swizzled
  int su = (t & 7) ^ ((t >> 3) & 7);
  int srow = 2 * (t >> 3) + (su >> 2);
  int scol = (su & 3) << 4;
  int sdst = t << 4;
  const unsigned char* gA0 = A + (size_t)(brow + srow) * K_DIM + scol;
  const unsigned char* gA1 = gA0 + (size_t)128 * K_DIM;

  // B direct: wave's two chunks for tile T at gB + {0,131072} + T*2048 + lane*32
  const unsigned char* gB =
      Bq + ((size_t)((bcol >> 5) + wn * 2) * 64) * 2048 + (size_t)lane * 32;

  // A fragment reads: row base+r5, bytes khalf*32..+31 as two b128 at
  // swizzled 16B slots.
  int kq0 = khalf << 1;
  int mac = (r5 >> 1) & 7;
  int slot0 = (((((r5 & 1) << 2) | kq0) ^ mac) << 4);
  int slot1 = (((((r5 & 1) << 2) | (kq0 + 1)) ^ mac) << 4);
  int arow = (wm * 64 + (r5 >> 1)) * 128;   // + m*2048 per subtile

  auto STAGE = [&](int T, int part) {
    unsigned char* dst = &lds[T & 3][part * 8192] + sdst;
    const unsigned char* src = (part == 0 ? gA0 : gA1) + T * BKB;
    GLOAD(src, dst);
  };

  auto FRAG = [&](const unsigned char* buf, int base) -> v8i {
    v4i lo = *(const v4i*)(buf + base + slot0);
    v4i hi = *(const v4i*)(buf + base + slot1);
    return __builtin_shufflevector(lo, hi, 0, 1, 2, 3, 4, 5, 6, 7);
  };

  auto BFRAG = [&](int n, int T) -> v8i {
    const v4i* p = (const v4i*)(gB + (size_t)n * 131072 + (size_t)T * 2048);
    v4i lo = p[0];
    v4i hi = p[1];
    return __builtin_shufflevector(lo, hi, 0, 1, 2, 3, 4, 5, 6, 7);
  };

  v16f acc[4][2] = {};

  // prologue: stage A tiles 0,1,2; load B(0); drain everything once; barrier.
#pragma unroll
  for (int T = 0; T < 3; ++T) { STAGE(T, 0); STAGE(T, 1); }
  v8i b0 = BFRAG(0, 0), b1 = BFRAG(1, 0);
  asm volatile("s_waitcnt vmcnt(0)" ::: "memory");
  __builtin_amdgcn_s_barrier();

  v8i a0 = FRAG(lds[0], arow);
  v8i a1 = FRAG(lds[0], arow + 2048);
  v8i a2 = FRAG(lds[0], arow + 2 * 2048);
  v8i a3 = FRAG(lds[0], arow + 3 * 2048);

  for (int T = 0; T < NT; ++T) {
    bool st = (T + 3) < NT;
    bool nx = (T + 1) < NT;

    if (st) { STAGE(T + 3, 0); STAGE(T + 3, 1); }

    v8i a0n, a1n, a2n, a3n, b0n, b1n;
    if (nx) {
      b0n = BFRAG(0, T + 1);
      b1n = BFRAG(1, T + 1);
      const unsigned char* bufn = lds[(T + 1) & 3];
      a0n = FRAG(bufn, arow);
      a1n = FRAG(bufn, arow + 2048);
      a2n = FRAG(bufn, arow + 2 * 2048);
      a3n = FRAG(bufn, arow + 3 * 2048);
    }

    __builtin_amdgcn_s_setprio(1);
    acc[0][0] = MFMA_SC(a0, b0, acc[0][0]);
    acc[0][1] = MFMA_SC(a0, b1, acc[0][1]);
    acc[1][0] = MFMA_SC(a1, b0, acc[1][0]);
    acc[1][1] = MFMA_SC(a1, b1, acc[1][1]);
    acc[2][0] = MFMA_SC(a2, b0, acc[2][0]);
    acc[2][1] = MFMA_SC(a2, b1, acc[2][1]);
    acc[3][0] = MFMA_SC(a3, b0, acc[3][0]);
    acc[3][1] = MFMA_SC(a3, b1, acc[3][1]);
    __builtin_amdgcn_s_setprio(0);

    // boundary: steady state keeps this iter's 6 VMEM ops (2 stages + 4
    // B-loads) in flight; everything older (incl. stage(T+2)) has retired
    // before the barrier -> slot (T+2)&3 globally valid next iter.
    if (st) {
      asm volatile("s_waitcnt vmcnt(6)" ::: "memory");
      __builtin_amdgcn_s_barrier();
    } else if (T == NT - 3) {
      asm volatile("s_waitcnt vmcnt(4)" ::: "memory");
      __builtin_amdgcn_s_barrier();
    }
    // T >= NT-2: no staging remains; no barrier needed.

    a0 = a0n; a1 = a1n; a2 = a2n; a3 = a3n;
    b0 = b0n; b1 = b1n;
  }

  // epilogue: 32x32 C/D map: col = lane&31, row = (reg&3)+8*(reg>>2)+4*(lane>>5)
  float scale = load_scale(amax_bits) * load_scale(amax_bits + 1);
  float* Cp = C + (size_t)(brow + wm * 128 + khalf * 4) * N_DIM +
              (bcol + wn * 64 + r5);
#pragma unroll
  for (int m = 0; m < 4; ++m)
#pragma unroll
    for (int r = 0; r < 16; ++r) {
      size_t ro = (size_t)(m * 32 + (r & 3) + 8 * (r >> 2)) * N_DIM;
#pragma unroll
      for (int n = 0; n < 2; ++n)
        Cp[ro + n * 32] = acc[m][n][r] * scale;
    }
}

// ----------------------------------------------------------------- launch ---
extern "C" void kernel_launch(void* const* d_in, const int* in_sizes, int n_in,
                              void* d_out, int out_size, void* d_ws,
                              size_t ws_size, hipStream_t stream) {
  const float* in1 = (const float*)d_in[0];
  const float* in2 = (const float*)d_in[1];
  float* out = (float*)d_out;
  unsigned char* ws = (unsigned char*)d_ws;

  const int R = in_sizes[0] / K_DIM;  // 16384
  const size_t qa_bytes = (size_t)R * K_DIM;
  const size_t qb_bytes = (size_t)N_DIM * K_DIM;
  const size_t need = 256 + qa_bytes + qb_bytes;
  if (ws_size < need) {
    fprintf(stderr, "kernel_launch: ws_size %zu < needed %zu\n", ws_size, need);
    return;
  }
  unsigned* amax = (unsigned*)ws;
  unsigned char* q1 = ws + 256;
  unsigned char* q2t = q1 + qa_bytes;

  hipMemsetAsync(ws, 0, 8, stream);
  amax_kernel<<<2048, 256, 0, stream>>>((const float4*)in1, in_sizes[0] / 4, amax);
  amax_kernel<<<1024, 256, 0, stream>>>((const float4*)in2, in_sizes[1] / 4, amax + 1);
  quant1_kernel<<<2048, 256, 0, stream>>>((const float4*)in1, (uint4*)q1, amax,
                                          in_sizes[0] / 16);
  quant2t_kernel<<<(K_DIM / 64) * (N_DIM / 64), 256, 0, stream>>>(in2, q2t, amax + 1);
  gemm_fp8_kernel<<<(R / 256) * (N_DIM / 256), 512, 0, stream>>>(q1, q2t, out, amax);
}

// Round 6
// 472.685 us; speedup vs baseline: 1.0173x; 1.0173x over previous
//
#include <hip/hip_runtime.h>
#include <hip/hip_fp8.h>
#include <cstdio>
#include <cstdint>

#define K_DIM 4096
#define N_DIM 4096
#define BKB 64                 // K-bytes per LDS tile
#define NT (K_DIM / BKB)       // 64 K-tiles

typedef int v4i __attribute__((ext_vector_type(4)));
typedef int v8i __attribute__((ext_vector_type(8)));
typedef float v16f __attribute__((ext_vector_type(16)));

// ---------------------------------------------------------------- amax ------
__global__ void amax_kernel(const float4* __restrict__ x, int n4,
                            unsigned* __restrict__ out) {
  int i = blockIdx.x * blockDim.x + threadIdx.x;
  int stride = gridDim.x * blockDim.x;
  float m = 0.f;
  for (; i < n4; i += stride) {
    float4 v = x[i];
    m = fmaxf(m, fmaxf(fmaxf(fabsf(v.x), fabsf(v.y)),
                       fmaxf(fabsf(v.z), fabsf(v.w))));
  }
#pragma unroll
  for (int off = 32; off > 0; off >>= 1)
    m = fmaxf(m, __shfl_down(m, off, 64));
  __shared__ float wred[4];
  int lane = threadIdx.x & 63, wid = threadIdx.x >> 6;
  if (lane == 0) wred[wid] = m;
  __syncthreads();
  if (threadIdx.x == 0) {
    m = fmaxf(fmaxf(wred[0], wred[1]), fmaxf(wred[2], wred[3]));
    atomicMax(out, __float_as_uint(m));  // bit-compare valid: m >= 0
  }
}

__device__ __forceinline__ float load_scale(const unsigned* p) {
  return fmaxf(__uint_as_float(*p) / 448.0f, 1e-12f);
}

__device__ __forceinline__ unsigned f2fp8(float v) {
  return (unsigned)__hip_cvt_float_to_fp8(v, __HIP_SATFINITE, __HIP_E4M3);
}

// ------------------------------------------------------------- quantize A ---
__global__ void quant1_kernel(const float4* __restrict__ x, uint4* __restrict__ q,
                              const unsigned* __restrict__ amax_bits, int n16) {
  float s = load_scale(amax_bits);
  int i = blockIdx.x * blockDim.x + threadIdx.x;
  int stride = gridDim.x * blockDim.x;
  for (; i < n16; i += stride) {
    unsigned w[4];
#pragma unroll
    for (int j = 0; j < 4; ++j) {
      float4 v = x[i * 4 + j];
      w[j] = f2fp8(v.x / s) | (f2fp8(v.y / s) << 8) |
             (f2fp8(v.z / s) << 16) | (f2fp8(v.w / s) << 24);
    }
    uint4 r; r.x = w[0]; r.y = w[1]; r.z = w[2]; r.w = w[3];
    q[i] = r;
  }
}

// ---------------------------- quantize B -> MFMA-fragment-blocked layout ----
// x: [K][N] fp32 -> Bq[n32][k64][lane][32B]: chunk (n32,k64) is the 2048-B
// fragment a wave consumes for B-subtile n32 at K-tile k64: lane l = kh*32+r5
// holds Bt[n32*32+r5][k64*64 + kh*32 .. +31]. Wave load = base + lane*32.
__global__ void quant2t_kernel(const float* __restrict__ x,
                               unsigned char* __restrict__ qt,
                               const unsigned* __restrict__ amax_bits) {
  float s = load_scale(amax_bits);
  __shared__ unsigned char tile[64][68];
  int tj = blockIdx.x & 63;   // N tile (2 chunks of 32)
  int ti = blockIdx.x >> 6;   // K tile
  int t = threadIdx.x;
  int c = t & 63;
  int r0 = (t >> 6) * 16;
#pragma unroll
  for (int rr = 0; rr < 16; ++rr) {
    int r = r0 + rr;
    float v = x[(size_t)(ti * 64 + r) * N_DIM + tj * 64 + c];
    tile[c][r] = (unsigned char)f2fp8(v / s);  // tile[n][k]
  }
  __syncthreads();
  int n = t >> 2;             // 0..63
  int kc = (t & 3) << 4;      // 0,16,32,48
  const unsigned* lp = (const unsigned*)&tile[n][kc];
  uint4 v; v.x = lp[0]; v.y = lp[1]; v.z = lp[2]; v.w = lp[3];
  int n32 = tj * 2 + (n >> 5);
  size_t dst = ((size_t)n32 * 64 + ti) * 2048 +
               (size_t)(((kc >> 5) * 32 + (n & 31)) * 32 + (kc & 31));
  *(uint4*)&qt[dst] = v;
}

// ------------------------------------------------------------------ GEMM ----
// 256x256 tile, 8 waves (2Mx4N), BK=64B, MX-scaled fp8 MFMA (scale exp 127 =
// exact 1.0) at 2x non-scaled fp8 rate.
// XCD COLUMN-PAIR GROUPING: XCD x (= bid&7, round-robin dispatch) owns output
// columns {2x,2x+1}, interleaved by row. B working set per XCD = 2 fragment-
// blocked panels = 2MB -> XCD-L2-resident; each A-panel is read across the
// fabric once and L2-hits for the sibling column. Fabric traffic ~2.1GB->0.6GB.
// A: LDS ring-4 x 16KB via global_load_lds (linear dest, pre-swizzled source),
//    staged 3 tiles ahead; fragments ds_read one tile ahead.
// B: global->register from fragment-blocked Bq (local L2), one tile ahead.
#define GLOAD(src, dst)                                              \
  __builtin_amdgcn_global_load_lds(                                  \
      (const __attribute__((address_space(1))) void*)(src),          \
      (__attribute__((address_space(3))) void*)(dst), 16, 0, 0)

#define MFMA_SC(a, b, c)                                             \
  __builtin_amdgcn_mfma_scale_f32_32x32x64_f8f6f4(a, b, c, 0, 0, 0, 127, 0, 127)

__global__ __launch_bounds__(512, 2)
void gemm_fp8_kernel(const unsigned char* __restrict__ A,
                     const unsigned char* __restrict__ Bq,
                     float* __restrict__ C,
                     const unsigned* __restrict__ amax_bits) {
  __shared__ __align__(16) unsigned char lds[4][16384];

  int bid = blockIdx.x;
  // XCD column-pair grouping: xcd = bid&7 -> bcols {2x,2x+1}; rows interleave
  // so the col-pair sharing one A-panel runs back-to-back on the same XCD.
  int xcd = bid & 7;
  int j = bid >> 3;                       // 0..127
  int brow = (j >> 1) * 256;              // 64 rows
  int bcol = (xcd * 2 + (j & 1)) * 256;   // 16 cols

  int t = threadIdx.x;
  int lane = t & 63, wid = t >> 6;
  int wm = wid >> 2, wn = wid & 3;        // wave quadrant: 2M x 4N
  int r5 = lane & 31;
  int khalf = lane >> 5;

  // A staging: dest linear (part*8192 + t*16), source column pre-swizzled
  int su = (t & 7) ^ ((t >> 3) & 7);
  int srow = 2 * (t >> 3) + (su >> 2);
  int scol = (su & 3) << 4;
  int sdst = t << 4;
  const unsigned char* gA0 = A + (size_t)(brow + srow) * K_DIM + scol;
  const unsigned char* gA1 = gA0 + (size_t)128 * K_DIM;

  // B direct: wave's two chunks for tile T at gB + {0,131072} + T*2048 + lane*32
  const unsigned char* gB =
      Bq + ((size_t)((bcol >> 5) + wn * 2) * 64) * 2048 + (size_t)lane * 32;

  // A fragment reads: row base+r5, bytes khalf*32..+31 as two b128 at
  // swizzled 16B slots.
  int kq0 = khalf << 1;
  int mac = (r5 >> 1) & 7;
  int slot0 = (((((r5 & 1) << 2) | kq0) ^ mac) << 4);
  int slot1 = (((((r5 & 1) << 2) | (kq0 + 1)) ^ mac) << 4);
  int arow = (wm * 64 + (r5 >> 1)) * 128;   // + m*2048 per subtile

  auto STAGE = [&](int T, int part) {
    unsigned char* dst = &lds[T & 3][part * 8192] + sdst;
    const unsigned char* src = (part == 0 ? gA0 : gA1) + T * BKB;
    GLOAD(src, dst);
  };

  auto FRAG = [&](const unsigned char* buf, int base) -> v8i {
    v4i lo = *(const v4i*)(buf + base + slot0);
    v4i hi = *(const v4i*)(buf + base + slot1);
    return __builtin_shufflevector(lo, hi, 0, 1, 2, 3, 4, 5, 6, 7);
  };

  auto BFRAG = [&](int n, int T) -> v8i {
    const v4i* p = (const v4i*)(gB + (size_t)n * 131072 + (size_t)T * 2048);
    v4i lo = p[0];
    v4i hi = p[1];
    return __builtin_shufflevector(lo, hi, 0, 1, 2, 3, 4, 5, 6, 7);
  };

  v16f acc[4][2] = {};

  // prologue: stage A tiles 0,1,2; load B(0); drain everything once; barrier.
#pragma unroll
  for (int T = 0; T < 3; ++T) { STAGE(T, 0); STAGE(T, 1); }
  v8i b0 = BFRAG(0, 0), b1 = BFRAG(1, 0);
  asm volatile("s_waitcnt vmcnt(0)" ::: "memory");
  __builtin_amdgcn_s_barrier();

  v8i a0 = FRAG(lds[0], arow);
  v8i a1 = FRAG(lds[0], arow + 2048);
  v8i a2 = FRAG(lds[0], arow + 2 * 2048);
  v8i a3 = FRAG(lds[0], arow + 3 * 2048);

  for (int T = 0; T < NT; ++T) {
    bool st = (T + 3) < NT;
    bool nx = (T + 1) < NT;

    // issue next-tile B loads first (oldest in queue; local-L2 latency hides
    // under this tile's MFMA cluster)
    v8i a0n, a1n, a2n, a3n, b0n, b1n;
    if (nx) {
      b0n = BFRAG(0, T + 1);
      b1n = BFRAG(1, T + 1);
    }
    if (st) { STAGE(T + 3, 0); STAGE(T + 3, 1); }
    if (nx) {
      const unsigned char* bufn = lds[(T + 1) & 3];
      a0n = FRAG(bufn, arow);
      a1n = FRAG(bufn, arow + 2048);
      a2n = FRAG(bufn, arow + 2 * 2048);
      a3n = FRAG(bufn, arow + 3 * 2048);
    }

    __builtin_amdgcn_s_setprio(1);
    acc[0][0] = MFMA_SC(a0, b0, acc[0][0]);
    acc[0][1] = MFMA_SC(a0, b1, acc[0][1]);
    acc[1][0] = MFMA_SC(a1, b0, acc[1][0]);
    acc[1][1] = MFMA_SC(a1, b1, acc[1][1]);
    acc[2][0] = MFMA_SC(a2, b0, acc[2][0]);
    acc[2][1] = MFMA_SC(a2, b1, acc[2][1]);
    acc[3][0] = MFMA_SC(a3, b0, acc[3][0]);
    acc[3][1] = MFMA_SC(a3, b1, acc[3][1]);
    __builtin_amdgcn_s_setprio(0);

    // boundary: steady state keeps this iter's 6 VMEM ops (4 B-loads + 2
    // stages) in flight; everything older (incl. stage(T+2)) has retired
    // before the barrier -> slot (T+2)&3 globally valid next iter.
    if (st) {
      asm volatile("s_waitcnt vmcnt(6)" ::: "memory");
      __builtin_amdgcn_s_barrier();
    } else if (T == NT - 3) {
      asm volatile("s_waitcnt vmcnt(4)" ::: "memory");
      __builtin_amdgcn_s_barrier();
    }
    // T >= NT-2: no staging remains; no barrier needed.

    a0 = a0n; a1 = a1n; a2 = a2n; a3 = a3n;
    b0 = b0n; b1 = b1n;
  }

  // epilogue: 32x32 C/D map: col = lane&31, row = (reg&3)+8*(reg>>2)+4*(lane>>5)
  float scale = load_scale(amax_bits) * load_scale(amax_bits + 1);
  float* Cp = C + (size_t)(brow + wm * 128 + khalf * 4) * N_DIM +
              (bcol + wn * 64 + r5);
#pragma unroll
  for (int m = 0; m < 4; ++m)
#pragma unroll
    for (int r = 0; r < 16; ++r) {
      size_t ro = (size_t)(m * 32 + (r & 3) + 8 * (r >> 2)) * N_DIM;
#pragma unroll
      for (int n = 0; n < 2; ++n)
        Cp[ro + n * 32] = acc[m][n][r] * scale;
    }
}

// ----------------------------------------------------------------- launch ---
extern "C" void kernel_launch(void* const* d_in, const int* in_sizes, int n_in,
                              void* d_out, int out_size, void* d_ws,
                              size_t ws_size, hipStream_t stream) {
  const float* in1 = (const float*)d_in[0];
  const float* in2 = (const float*)d_in[1];
  float* out = (float*)d_out;
  unsigned char* ws = (unsigned char*)d_ws;

  const int R = in_sizes[0] / K_DIM;  // 16384
  const size_t qa_bytes = (size_t)R * K_DIM;
  const size_t qb_bytes = (size_t)N_DIM * K_DIM;
  const size_t need = 256 + qa_bytes + qb_bytes;
  if (ws_size < need) {
    fprintf(stderr, "kernel_launch: ws_size %zu < needed %zu\n", ws_size, need);
    return;
  }
  unsigned* amax = (unsigned*)ws;
  unsigned char* q1 = ws + 256;
  unsigned char* q2t = q1 + qa_bytes;

  hipMemsetAsync(ws, 0, 8, stream);
  amax_kernel<<<2048, 256, 0, stream>>>((const float4*)in1, in_sizes[0] / 4, amax);
  amax_kernel<<<1024, 256, 0, stream>>>((const float4*)in2, in_sizes[1] / 4, amax + 1);
  quant1_kernel<<<2048, 256, 0, stream>>>((const float4*)in1, (uint4*)q1, amax,
                                          in_sizes[0] / 16);
  quant2t_kernel<<<(K_DIM / 64) * (N_DIM / 64), 256, 0, stream>>>(in2, q2t, amax + 1);
  gemm_fp8_kernel<<<(R / 256) * (N_DIM / 256), 512, 0, stream>>>(q1, q2t, out, amax);
}